// Round 2
// baseline (947.714 us; speedup 1.0000x reference)
//
#include <hip/hip_runtime.h>

#define PLANE 1042441      // 1021*1021
#define S1 255             // h1 even-grid spatial (h1e)
#define S2 253             // h2 spatial
#define NOUT 66716224      // 8*8*1021*1021
#define NCHUNK4 16679056   // NOUT/4

// R[co*4 + pc] = sum_ci relu(b3[ci]) * sum_{(jy,jx) off-core for pc} w4[co][ci][jy][jx]
// pc = (py&1)*2 + (px&1); core jy = {0,2} if py even else {1}; same for jx.
__global__ void k_setup(const float* __restrict__ w4, const float* __restrict__ b3_,
                        float* __restrict__ R) {
  int t = threadIdx.x;
  if (t >= 32) return;
  int co = t >> 2, pc = t & 3;
  float s = 0.f;
  for (int ci = 0; ci < 8; ++ci) {
    float r3 = fmaxf(b3_[ci], 0.f);
    float wsum = 0.f;
    for (int jy = 0; jy < 3; ++jy)
      for (int jx = 0; jx < 3; ++jx) {
        bool cy = (pc & 2) ? (jy == 1) : (jy != 1);
        bool cx = (pc & 1) ? (jx == 1) : (jx != 1);
        if (!(cy && cx)) wsum += w4[(co * 8 + ci) * 9 + jy * 3 + jx];
      }
    s += r3 * wsum;
  }
  R[t] = s;
}

// h1e[n][co][m][t] = relu(b1 + sum x[n][ci][4m+2ky][4t+2kx]*w1), 255x255
__global__ void k_conv1(const float* __restrict__ x, const float* __restrict__ w1,
                        const float* __restrict__ b1_, float* __restrict__ h1e) {
  int t = blockIdx.x * 64 + threadIdx.x;
  int m = blockIdx.y * 4 + threadIdx.y;
  int z = blockIdx.z;                 // n*8+co
  if (t >= S1 || m >= S1) return;
  int n = z >> 3, co = z & 7;
  float acc = b1_[co];
  const float* wp = w1 + co * 27;
  const float* xn = x + (size_t)n * 3 * PLANE;
#pragma unroll
  for (int ci = 0; ci < 3; ++ci) {
    const float* xc = xn + ci * PLANE;
#pragma unroll
    for (int ky = 0; ky < 3; ++ky) {
      const float* xr = xc + (4 * m + 2 * ky) * 1021 + 4 * t;
#pragma unroll
      for (int kx = 0; kx < 3; ++kx)
        acc = fmaf(xr[2 * kx], wp[(ci * 3 + ky) * 3 + kx], acc);
    }
  }
  h1e[((size_t)z * S1 + m) * S1 + t] = fmaxf(acc, 0.f);
}

// h2[n][co16][u][v] = relu(b2 + sum h1e[n][ci][u+ky][v+kx]*w2), 253x253
__global__ void k_conv2(const float* __restrict__ h1e, const float* __restrict__ w2,
                        const float* __restrict__ b2_, float* __restrict__ h2) {
  int v = blockIdx.x * 64 + threadIdx.x;
  int u = blockIdx.y * 4 + threadIdx.y;
  int z = blockIdx.z;                 // n*16+co
  if (v >= S2 || u >= S2) return;
  int n = z >> 4, co = z & 15;
  float acc = b2_[co];
  const float* wp = w2 + co * 72;
  const float* hn = h1e + (size_t)n * 8 * S1 * S1;
  for (int ci = 0; ci < 8; ++ci) {
    const float* hc = hn + ci * S1 * S1;
#pragma unroll
    for (int ky = 0; ky < 3; ++ky) {
      const float* hr = hc + (u + ky) * S1 + v;
#pragma unroll
      for (int kx = 0; kx < 3; ++kx)
        acc = fmaf(hr[kx], wp[(ci * 3 + ky) * 3 + kx], acc);
    }
  }
  h2[((size_t)z * S2 + u) * S2 + v] = fmaxf(acc, 0.f);
}

// h3core[n][co][q][r] = relu(b3 + sum_{valid} h2[n][ci][q-jy][r-jx]*w3), 255x255
__global__ void k_deconv3(const float* __restrict__ h2, const float* __restrict__ w3,
                          const float* __restrict__ b3_, float* __restrict__ h3c) {
  int r = blockIdx.x * 64 + threadIdx.x;
  int q = blockIdx.y * 4 + threadIdx.y;
  int z = blockIdx.z;                 // n*8+co
  if (r >= S1 || q >= S1) return;
  int n = z >> 3, co = z & 7;
  float acc = b3_[co];
  const float* wp = w3 + co * 16 * 9;
  const float* hn = h2 + (size_t)n * 16 * S2 * S2;
  for (int ci = 0; ci < 16; ++ci) {
    const float* hc = hn + ci * S2 * S2;
#pragma unroll
    for (int jy = 0; jy < 3; ++jy) {
      int a = q - jy;
      if ((unsigned)a > 252u) continue;
#pragma unroll
      for (int jx = 0; jx < 3; ++jx) {
        int b = r - jx;
        if ((unsigned)b > 252u) continue;
        acc = fmaf(hc[a * S2 + b], wp[(ci * 3 + jy) * 3 + jx], acc);
      }
    }
  }
  h3c[((size_t)z * S1 + q) * S1 + r] = fmaxf(acc, 0.f);
}

// Fill entire output with per-plane constant b4[co] (odd-parity positions are
// exactly b4; even-even gets overwritten by k_deconv4 afterwards).
__global__ void k_fill(const float* __restrict__ b4_, float* __restrict__ out) {
  int c = blockIdx.x * 256 + threadIdx.x;
  if (c >= NCHUNK4) return;
  size_t first = (size_t)c * 4u;
  unsigned p0 = (unsigned)(first / PLANE);
  unsigned p1 = (unsigned)((first + 3u) / PLANE);
  if (p0 == p1) {
    float cb = b4_[p0 & 7u];
    float4 val = make_float4(cb, cb, cb, cb);
    *(float4*)(out + first) = val;    // first multiple of 4 floats -> 16B aligned
  } else {
    for (int i = 0; i < 4; ++i) {
      size_t idx = first + i;
      out[idx] = b4_[(idx / PLANE) & 7u];
    }
  }
}

// Final even-even outputs: out[n][co][2py][2px], py,px in [0,511).
// out = b4 + sum_{ci,jy,jx} H3(py-jy, px-jx) * w4[co][ci][jy][jx]
// H3(a,b): oob -> 0 ; both even -> h3core[a/2][b/2] ; else relu(b3[ci]).
// Threads own a 2x2 block of (py,px): {2i,2i+1} x {2j,2j+1}.
__global__ void k_deconv4(const float* __restrict__ h3c, const float* __restrict__ w4,
                          const float* __restrict__ b4_, const float* __restrict__ b3_,
                          const float* __restrict__ R, float* __restrict__ out) {
  int j = blockIdx.x * 64 + threadIdx.x;   // 0..255
  int i = blockIdx.y * 4 + threadIdx.y;    // 0..255
  int z = blockIdx.z;                      // n*8+co
  int n = z >> 3, co = z & 7;
  const float* hn = h3c + (size_t)n * 8 * S1 * S1;
  const float* wp = w4 + co * 72;
  float b4f = b4_[co];
  float* op = out + (size_t)z * PLANE;
  if (i >= 1 && i <= 253 && j >= 1 && j <= 253) {
    // interior fast path: all taps in-bounds, off-core taps folded into R
    float s_ee = 0.f, s_eo = 0.f, s_oe = 0.f, s_oo = 0.f;
    for (int ci = 0; ci < 8; ++ci) {
      const float* hcc = hn + ci * (S1 * S1) + i * S1 + j;
      float c11 = hcc[0], c10 = hcc[-1], c01 = hcc[-S1], c00 = hcc[-S1 - 1];
      const float* w = wp + ci * 9;
      float w00 = w[0], w01 = w[1], w02 = w[2];
      float w10 = w[3], w11 = w[4], w12 = w[5];
      float w20 = w[6], w21 = w[7], w22 = w[8];
      s_ee = fmaf(c11, w00, fmaf(c10, w02, fmaf(c01, w20, fmaf(c00, w22, s_ee))));
      s_eo = fmaf(c11, w01, fmaf(c01, w21, s_eo));
      s_oe = fmaf(c11, w10, fmaf(c10, w12, s_oe));
      s_oo = fmaf(c11, w11, s_oo);
    }
    int y0 = 4 * i, x0 = 4 * j;
    op[(size_t)y0 * 1021 + x0]           = b4f + R[co * 4 + 0] + s_ee;
    op[(size_t)y0 * 1021 + x0 + 2]       = b4f + R[co * 4 + 1] + s_eo;
    op[(size_t)(y0 + 2) * 1021 + x0]     = b4f + R[co * 4 + 2] + s_oe;
    op[(size_t)(y0 + 2) * 1021 + x0 + 2] = b4f + R[co * 4 + 3] + s_oo;
  } else {
    // border path: general tap classification
    for (int dy = 0; dy < 2; ++dy)
      for (int dx = 0; dx < 2; ++dx) {
        int py = 2 * i + dy, px = 2 * j + dx;
        if (py > 510 || px > 510) continue;
        float acc = b4f;
        for (int ci = 0; ci < 8; ++ci) {
          float r3 = fmaxf(b3_[ci], 0.f);
          const float* hcc = hn + ci * (S1 * S1);
#pragma unroll
          for (int jy = 0; jy < 3; ++jy) {
            int a = py - jy;
#pragma unroll
            for (int jx = 0; jx < 3; ++jx) {
              int b = px - jx;
              float h;
              if ((unsigned)a > 508u || (unsigned)b > 508u) h = 0.f;
              else if (((a | b) & 1) == 0) h = hcc[(a >> 1) * S1 + (b >> 1)];
              else h = r3;
              acc = fmaf(h, wp[ci * 9 + jy * 3 + jx], acc);
            }
          }
        }
        op[(size_t)(2 * py) * 1021 + 2 * px] = acc;
      }
  }
}

extern "C" void kernel_launch(void* const* d_in, const int* in_sizes, int n_in,
                              void* d_out, int out_size, void* d_ws, size_t ws_size,
                              hipStream_t stream) {
  const float* x   = (const float*)d_in[0];
  const float* w1  = (const float*)d_in[1];
  const float* b1_ = (const float*)d_in[2];
  const float* w2  = (const float*)d_in[3];
  const float* b2_ = (const float*)d_in[4];
  const float* w3  = (const float*)d_in[5];
  const float* b3_ = (const float*)d_in[6];
  const float* w4  = (const float*)d_in[7];
  const float* b4_ = (const float*)d_in[8];
  float* out = (float*)d_out;

  // ws layout (fp32): h1e 8*8*255*255 | h2 8*16*253*253 | h3core 8*8*255*255 | R 32
  // total = 66,065,536 bytes
  float* h1e = (float*)d_ws;
  float* h2  = h1e + (size_t)8 * 8 * S1 * S1;
  float* h3c = h2 + (size_t)8 * 16 * S2 * S2;
  float* R   = h3c + (size_t)8 * 8 * S1 * S1;

  dim3 blk(64, 4, 1);
  k_setup<<<1, 64, 0, stream>>>(w4, b3_, R);
  k_conv1<<<dim3(4, 64, 64), blk, 0, stream>>>(x, w1, b1_, h1e);
  k_conv2<<<dim3(4, 64, 128), blk, 0, stream>>>(h1e, w2, b2_, h2);
  k_deconv3<<<dim3(4, 64, 64), blk, 0, stream>>>(h2, w3, b3_, h3c);
  k_fill<<<(NCHUNK4 + 255) / 256, 256, 0, stream>>>(b4_, out);
  k_deconv4<<<dim3(4, 64, 64), blk, 0, stream>>>(h3c, w4, b4_, b3_, R, out);
}

// Round 3
// 680.021 us; speedup vs baseline: 1.3937x; 1.3937x over previous
//
#include <hip/hip_runtime.h>

#define PLANE 1042441      // 1021*1021
#define S1 255             // h1 even-grid / h3 core spatial
#define S2 253             // h2 spatial
#define S1S1 65025
#define S2S2 64009
#define NOUT 66716224      // 8*8*1021*1021
#define NCHUNK4 16679056   // NOUT/4

// ws layout (floats): h1e[4161600] | h2[8193152] | h3c[4161600] | R[32] | WT[768]

// R[co*4+pc] = sum_ci relu(b3[ci]) * sum_{off-core taps for pc} w4[co][ci][jy][jx]
// WT[(co*8+ci)*12] = packed w4: [w00,w02,w20,w22, w01,w21,w10,w12, w11,0,0,0]
__global__ void k_setup(const float* __restrict__ w4, const float* __restrict__ b3_,
                        float* __restrict__ R, float* __restrict__ WT) {
  int t = threadIdx.x;
  if (t < 32) {
    int co = t >> 2, pc = t & 3;
    float s = 0.f;
    for (int ci = 0; ci < 8; ++ci) {
      float r3 = fmaxf(b3_[ci], 0.f);
      float wsum = 0.f;
      for (int jy = 0; jy < 3; ++jy)
        for (int jx = 0; jx < 3; ++jx) {
          bool cy = (pc & 2) ? (jy == 1) : (jy != 1);
          bool cx = (pc & 1) ? (jx == 1) : (jx != 1);
          if (!(cy && cx)) wsum += w4[(co * 8 + ci) * 9 + jy * 3 + jx];
        }
      s += r3 * wsum;
    }
    R[t] = s;
  }
  {
    int co = t >> 3, ci = t & 7;
    const float* w = w4 + (co * 8 + ci) * 9;
    float* d = WT + (co * 8 + ci) * 12;
    d[0] = w[0]; d[1] = w[2]; d[2] = w[6]; d[3] = w[8];
    d[4] = w[1]; d[5] = w[7]; d[6] = w[3]; d[7] = w[5];
    d[8] = w[4]; d[9] = 0.f; d[10] = 0.f; d[11] = 0.f;
  }
}

// h1e[n][co][m][t] = relu(b1 + sum x[n][ci][4m+2ky][4t+2kx]*w1), 255x255
__global__ void k_conv1(const float* __restrict__ x, const float* __restrict__ w1,
                        const float* __restrict__ b1_, float* __restrict__ h1e) {
  int t = blockIdx.x * 64 + threadIdx.x;
  int m = blockIdx.y * 4 + threadIdx.y;
  int z = blockIdx.z;                 // n*8+co
  if (t >= S1 || m >= S1) return;
  int n = z >> 3, co = z & 7;
  float acc = b1_[co];
  const float* wp = w1 + co * 27;
  const float* xn = x + (size_t)n * 3 * PLANE;
#pragma unroll
  for (int ci = 0; ci < 3; ++ci) {
    const float* xc = xn + ci * PLANE;
#pragma unroll
    for (int ky = 0; ky < 3; ++ky) {
      const float* xr = xc + (4 * m + 2 * ky) * 1021 + 4 * t;
#pragma unroll
      for (int kx = 0; kx < 3; ++kx)
        acc = fmaf(xr[2 * kx], wp[(ci * 3 + ky) * 3 + kx], acc);
    }
  }
  h1e[((size_t)z * S1 + m) * S1 + t] = fmaxf(acc, 0.f);
}

// h2: 4 pixels (v) x 4 co per thread. 16 independent accumulators.
__global__ __launch_bounds__(256) void k_conv2(const float* __restrict__ h1e,
    const float* __restrict__ w2, const float* __restrict__ b2_, float* __restrict__ h2) {
  int v0 = threadIdx.x * 4;                  // 0..252
  int u = blockIdx.y * 4 + threadIdx.y;
  int zb = blockIdx.z;                       // n*4 + cog'
  int n = zb >> 2, cog = (zb & 3) * 4;
  if (u >= S2) return;
  float acc[4][4];
#pragma unroll
  for (int cc = 0; cc < 4; ++cc) {
    float b = b2_[cog + cc];
#pragma unroll
    for (int p = 0; p < 4; ++p) acc[cc][p] = b;
  }
  const float* hn = h1e + (size_t)n * 8 * S1S1;
  for (int ci = 0; ci < 8; ++ci) {
    const float* hc = hn + ci * S1S1;
#pragma unroll
    for (int ky = 0; ky < 3; ++ky) {
      const float* hr = hc + (u + ky) * S1 + v0;
      float rr[6];
#pragma unroll
      for (int q = 0; q < 6; ++q) rr[q] = hr[q];  // may read past row end: only feeds invalid outputs
#pragma unroll
      for (int cc = 0; cc < 4; ++cc) {
        const float* w = w2 + (cog + cc) * 72 + ci * 9 + ky * 3;
        float w0 = w[0], w1 = w[1], w2v = w[2];
#pragma unroll
        for (int p = 0; p < 4; ++p)
          acc[cc][p] = fmaf(rr[p], w0, fmaf(rr[p + 1], w1, fmaf(rr[p + 2], w2v, acc[cc][p])));
      }
    }
  }
#pragma unroll
  for (int cc = 0; cc < 4; ++cc) {
    float* op = h2 + ((size_t)(n * 16 + cog + cc) * S2 + u) * S2 + v0;
#pragma unroll
    for (int p = 0; p < 4; ++p)
      if (v0 + p < S2) op[p] = fmaxf(acc[cc][p], 0.f);
  }
}

// h3core: 4 pixels (r) x 4 co per thread.
__global__ __launch_bounds__(256) void k_deconv3(const float* __restrict__ h2,
    const float* __restrict__ w3, const float* __restrict__ b3_, float* __restrict__ h3c) {
  int r0 = threadIdx.x * 4;                  // 0..252
  int q = blockIdx.y * 4 + threadIdx.y;
  int zb = blockIdx.z;                       // n*2 + g
  int n = zb >> 1, cog = (zb & 1) * 4;
  if (q >= S1) return;
  float acc[4][4];
#pragma unroll
  for (int cc = 0; cc < 4; ++cc) {
    float b = b3_[cog + cc];
#pragma unroll
    for (int p = 0; p < 4; ++p) acc[cc][p] = b;
  }
  const float* hn = h2 + (size_t)n * 16 * S2S2;
  bool inner = (r0 >= 4 && r0 <= 248);
  for (int ci = 0; ci < 16; ++ci) {
    const float* hc = hn + ci * S2S2;
#pragma unroll
    for (int jy = 0; jy < 3; ++jy) {
      int a = q - jy;
      if ((unsigned)a > 252u) continue;
      const float* hr = hc + a * S2 + (r0 - 2);
      float rr[6];
      if (inner) {
#pragma unroll
        for (int q2 = 0; q2 < 6; ++q2) rr[q2] = hr[q2];
      } else {
#pragma unroll
        for (int q2 = 0; q2 < 6; ++q2) {
          int col = r0 - 2 + q2;
          rr[q2] = ((unsigned)col <= 252u) ? hr[q2] : 0.f;
        }
      }
#pragma unroll
      for (int cc = 0; cc < 4; ++cc) {
        const float* w = w3 + ((cog + cc) * 16 + ci) * 9 + jy * 3;
        float w0 = w[0], w1 = w[1], w2v = w[2];
        // b = r0+p-jx -> rr[p-jx+2]
#pragma unroll
        for (int p = 0; p < 4; ++p)
          acc[cc][p] = fmaf(rr[p + 2], w0, fmaf(rr[p + 1], w1, fmaf(rr[p], w2v, acc[cc][p])));
      }
    }
  }
#pragma unroll
  for (int cc = 0; cc < 4; ++cc)
#pragma unroll
    for (int p = 0; p < 4; ++p)
      if (r0 + p < S1)
        h3c[((size_t)(n * 8 + cog + cc) * S1 + q) * S1 + r0 + p] = fmaxf(acc[cc][p], 0.f);
}

// General (border) per-element output value.
__device__ __forceinline__ float general_val(unsigned idx, const float* __restrict__ h3c,
    const float* __restrict__ w4, const float* __restrict__ b4_, const float* __restrict__ b3_) {
  unsigned z = idx / PLANE;
  unsigned rem = idx - z * PLANE;
  unsigned y = rem / 1021u;
  unsigned x = rem - y * 1021u;
  int co = z & 7;
  float acc = b4_[co];
  if ((y | x) & 1u) return acc;
  int py = y >> 1, px = x >> 1;
  const float* hn = h3c + (size_t)(z >> 3) * 8 * S1S1;
  const float* wp = w4 + co * 72;
  for (int ci = 0; ci < 8; ++ci) {
    float r3 = fmaxf(b3_[ci], 0.f);
    const float* hcc = hn + ci * S1S1;
#pragma unroll
    for (int jy = 0; jy < 3; ++jy) {
      int a = py - jy;
#pragma unroll
      for (int jx = 0; jx < 3; ++jx) {
        int b = px - jx;
        float h;
        if ((unsigned)a > 508u || (unsigned)b > 508u) h = 0.f;
        else if (((a | b) & 1) == 0) h = hcc[(a >> 1) * S1 + (b >> 1)];
        else h = r3;
        acc = fmaf(h, wp[ci * 9 + jy * 3 + jx], acc);
      }
    }
  }
  return acc;
}

// Single-pass output: every float4 chunk written exactly once, fully coalesced.
__global__ __launch_bounds__(256) void k_out(const float* __restrict__ h3c,
    const float* __restrict__ w4, const float* __restrict__ b4_,
    const float* __restrict__ b3_, const float* __restrict__ R,
    const float* __restrict__ WT, float* __restrict__ out) {
  unsigned c = blockIdx.x * 256 + threadIdx.x;
  if (c >= NCHUNK4) return;
  unsigned first = c * 4u;
  unsigned z = first / PLANE;
  unsigned rem = first - z * PLANE;
  unsigned y = rem / 1021u;
  unsigned x = rem - y * 1021u;
  if (x + 3u <= 1020u) {             // chunk within one row (hence one plane)
    int co = z & 7;
    float b4f = b4_[co];
    if (y & 1u) {                    // odd row: pure constant
      *(float4*)(out + first) = make_float4(b4f, b4f, b4f, b4f);
      return;
    }
    if (y >= 4u && y <= 1016u && x >= 3u && x <= 1013u) {
      // interior even row: 2 computed values at even x, 2 constants
      unsigned py = y >> 1;
      unsigned e0 = x + (x & 1u);            // first even x in chunk
      unsigned pxa = e0 >> 1;                // px of first computed value
      unsigned col0 = (pxa - 1u) >> 1;
      unsigned pxodd = pxa & 1u;
      const float* hn = h3c + (size_t)(z >> 3) * 8 * S1S1;
      const float* wt = WT + co * 96;
      float vE = 0.f, vO = 0.f, rE, rO;
      if ((py & 1u) == 0) {
        unsigned i = py >> 1;
        const float* hp = hn + (i - 1) * S1 + col0;
#pragma unroll
        for (int ci = 0; ci < 8; ++ci) {
          const float* p = hp + ci * S1S1;
          float m00 = p[0], m01 = p[1], m10 = p[S1], m11 = p[S1 + 1];
          float4 A = *(const float4*)(wt + ci * 12);
          float4 B = *(const float4*)(wt + ci * 12 + 4);
          vE = fmaf(m11, A.x, fmaf(m10, A.y, fmaf(m01, A.z, fmaf(m00, A.w, vE))));
          float t1 = pxodd ? m10 : m11;
          float t0 = pxodd ? m00 : m01;
          vO = fmaf(t1, B.x, fmaf(t0, B.y, vO));
        }
        rE = b4f + R[co * 4 + 0] + vE;
        rO = b4f + R[co * 4 + 1] + vO;
      } else {
        unsigned a = py >> 1;                // (py-1)/2 for odd py
        const float* hp = hn + a * S1 + col0;
#pragma unroll
        for (int ci = 0; ci < 8; ++ci) {
          const float* p = hp + ci * S1S1;
          float n0 = p[0], n1 = p[1];
          float4 B = *(const float4*)(wt + ci * 12 + 4);
          float w11 = wt[ci * 12 + 8];
          vE = fmaf(n1, B.z, fmaf(n0, B.w, vE));
          vO = fmaf(pxodd ? n0 : n1, w11, vO);
        }
        rE = b4f + R[co * 4 + 2] + vE;
        rO = b4f + R[co * 4 + 3] + vO;
      }
      float va = pxodd ? rO : rE;            // value at x = e0
      float vb = pxodd ? rE : rO;            // value at x = e0+2
      float4 v;
      if (x & 1u) v = make_float4(b4f, va, b4f, vb);
      else        v = make_float4(va, b4f, vb, b4f);
      *(float4*)(out + first) = v;
      return;
    }
  }
  // border / row-crossing / plane-crossing: per-element general path
#pragma unroll
  for (int k = 0; k < 4; ++k)
    out[first + k] = general_val(first + k, h3c, w4, b4_, b3_);
}

extern "C" void kernel_launch(void* const* d_in, const int* in_sizes, int n_in,
                              void* d_out, int out_size, void* d_ws, size_t ws_size,
                              hipStream_t stream) {
  const float* x   = (const float*)d_in[0];
  const float* w1  = (const float*)d_in[1];
  const float* b1_ = (const float*)d_in[2];
  const float* w2  = (const float*)d_in[3];
  const float* b2_ = (const float*)d_in[4];
  const float* w3  = (const float*)d_in[5];
  const float* b3_ = (const float*)d_in[6];
  const float* w4  = (const float*)d_in[7];
  const float* b4_ = (const float*)d_in[8];
  float* out = (float*)d_out;

  float* h1e = (float*)d_ws;
  float* h2  = h1e + (size_t)8 * 8 * S1S1;
  float* h3c = h2 + (size_t)8 * 16 * S2S2;
  float* R   = h3c + (size_t)8 * 8 * S1S1;
  float* WT  = R + 32;

  dim3 blk(64, 4, 1);
  k_setup<<<1, 64, 0, stream>>>(w4, b3_, R, WT);
  k_conv1<<<dim3(4, 64, 64), blk, 0, stream>>>(x, w1, b1_, h1e);
  k_conv2<<<dim3(1, 64, 32), blk, 0, stream>>>(h1e, w2, b2_, h2);
  k_deconv3<<<dim3(1, 64, 16), blk, 0, stream>>>(h2, w3, b3_, h3c);
  k_out<<<(NCHUNK4 + 255) / 256, 256, 0, stream>>>(h3c, w4, b4_, b3_, R, WT, out);
}